// Round 1
// baseline (211.046 us; speedup 1.0000x reference)
//
#include <hip/hip_runtime.h>
#include <hip/hip_bf16.h>
#include <math.h>

// Problem constants (fixed by the reference setup_inputs()).
#define B_SZ    16384
#define NNZ     32
#define FT_OUT  1024
#define FEAT    768
#define BUCKETS 8

// ---------------------------------------------------------------------------
// Kernel 1: transpose ft_w [FT_OUT][FEAT] -> ftT [FEAT][FT_OUT] (both fp32)
// so that a feature-column gather becomes a contiguous 4 KB row read.
// One-shot 3 MB: reads are strided but L2/L3-absorbed; writes coalesced.
// ---------------------------------------------------------------------------
__global__ void transpose_ftw(const float* __restrict__ ft_w,
                              float* __restrict__ ftT) {
    int idx = blockIdx.x * blockDim.x + threadIdx.x;   // 0 .. 768*1024-1
    int f = idx >> 10;        // feature   0..767
    int o = idx & 1023;       // ft output 0..1023
    ftT[idx] = ft_w[o * FEAT + f];
}

// ---------------------------------------------------------------------------
// Kernel 2: one wave (64 lanes) per board.
//   acc_stm = ft_b + sum_k v[k] * ftT[stm_f[k]][:]
//   acc_nstm likewise; hidden = clip(.,0,1); logit = dot(hidden, out_w[bkt]);
//   out[b] = sigmoid(logit + out_b[bkt]).
// Lane L owns outputs o = r*256 + L*4 + j  (r=0..3, j=0..3): each of the 4
// per-column loads is one fully-coalesced 1 KB wave transaction.
// ---------------------------------------------------------------------------
__global__ __launch_bounds__(256) void nn_fwd(
    const int*   __restrict__ stm_idx,   // [B*NNZ*2] (board, feat) pairs
    const int*   __restrict__ nstm_idx,  // [B*NNZ*2]
    const float* __restrict__ values,    // [B*NNZ]
    const int*   __restrict__ buckets,   // [B]
    const float* __restrict__ ftT,       // [FEAT][FT_OUT]
    const float* __restrict__ ft_b,      // [FT_OUT]
    const float* __restrict__ out_w,     // [BUCKETS][2*FT_OUT]
    const float* __restrict__ out_b,     // [BUCKETS]
    float*       __restrict__ out)       // [B]
{
    const int wave = threadIdx.x >> 6;
    const int lane = threadIdx.x & 63;
    // Wave-uniform board id -> scalar loads for indices/values/bucket.
    const int b = __builtin_amdgcn_readfirstlane(blockIdx.x * 4 + wave);

    float4 acc_s[4], acc_n[4];
#pragma unroll
    for (int r = 0; r < 4; ++r) {
        float4 bias = *(const float4*)(ft_b + r * 256 + lane * 4);
        acc_s[r] = bias;
        acc_n[r] = bias;
    }

    const int base = b * NNZ;

    // ---- stm accumulate ----
#pragma unroll 2
    for (int k = 0; k < NNZ; ++k) {
        const int   f = stm_idx[(base + k) * 2 + 1];
        const float v = values[base + k];
        const float* col = ftT + f * FT_OUT;
#pragma unroll
        for (int r = 0; r < 4; ++r) {
            float4 w = *(const float4*)(col + r * 256 + lane * 4);
            acc_s[r].x = fmaf(v, w.x, acc_s[r].x);
            acc_s[r].y = fmaf(v, w.y, acc_s[r].y);
            acc_s[r].z = fmaf(v, w.z, acc_s[r].z);
            acc_s[r].w = fmaf(v, w.w, acc_s[r].w);
        }
    }

    // ---- nstm accumulate ----
#pragma unroll 2
    for (int k = 0; k < NNZ; ++k) {
        const int   f = nstm_idx[(base + k) * 2 + 1];
        const float v = values[base + k];
        const float* col = ftT + f * FT_OUT;
#pragma unroll
        for (int r = 0; r < 4; ++r) {
            float4 w = *(const float4*)(col + r * 256 + lane * 4);
            acc_n[r].x = fmaf(v, w.x, acc_n[r].x);
            acc_n[r].y = fmaf(v, w.y, acc_n[r].y);
            acc_n[r].z = fmaf(v, w.z, acc_n[r].z);
            acc_n[r].w = fmaf(v, w.w, acc_n[r].w);
        }
    }

    // ---- epilogue: clip, bucket-row dot, wave reduce, sigmoid ----
    const int bkt = __builtin_amdgcn_readfirstlane(buckets[b]);
    const float* ow = out_w + bkt * (2 * FT_OUT);

    float part = 0.0f;
#pragma unroll
    for (int r = 0; r < 4; ++r) {
        float4 ws = *(const float4*)(ow + r * 256 + lane * 4);
        float4 wn = *(const float4*)(ow + FT_OUT + r * 256 + lane * 4);
        part += fminf(fmaxf(acc_s[r].x, 0.f), 1.f) * ws.x;
        part += fminf(fmaxf(acc_s[r].y, 0.f), 1.f) * ws.y;
        part += fminf(fmaxf(acc_s[r].z, 0.f), 1.f) * ws.z;
        part += fminf(fmaxf(acc_s[r].w, 0.f), 1.f) * ws.w;
        part += fminf(fmaxf(acc_n[r].x, 0.f), 1.f) * wn.x;
        part += fminf(fmaxf(acc_n[r].y, 0.f), 1.f) * wn.y;
        part += fminf(fmaxf(acc_n[r].z, 0.f), 1.f) * wn.z;
        part += fminf(fmaxf(acc_n[r].w, 0.f), 1.f) * wn.w;
    }
#pragma unroll
    for (int off = 32; off >= 1; off >>= 1)
        part += __shfl_xor(part, off);

    if (lane == 0) {
        float logit = part + out_b[bkt];
        out[b] = 1.0f / (1.0f + expf(-logit));
    }
}

// ---------------------------------------------------------------------------
// setup_inputs() order:
//   0 stm_indices [B*32,2] int   1 nstm_indices [B*32,2] int
//   2 values [B*32] f32          3 buckets [B] int
//   4 size (scalar)              5 ft_w [1024,768] f32
//   6 ft_b [1024] f32            7 out_w [8,2048] f32
//   8 out_b [8] f32
// ---------------------------------------------------------------------------
extern "C" void kernel_launch(void* const* d_in, const int* in_sizes, int n_in,
                              void* d_out, int out_size, void* d_ws, size_t ws_size,
                              hipStream_t stream) {
    const int*   stm_idx  = (const int*)  d_in[0];
    const int*   nstm_idx = (const int*)  d_in[1];
    const float* values   = (const float*)d_in[2];
    const int*   buckets  = (const int*)  d_in[3];
    const float* ft_w     = (const float*)d_in[5];
    const float* ft_b     = (const float*)d_in[6];
    const float* out_w    = (const float*)d_in[7];
    const float* out_b    = (const float*)d_in[8];
    float*       out      = (float*)d_out;

    float* ftT = (float*)d_ws;   // [768][1024] fp32 = 3 MB

    // Kernel 1: build transposed table (ws is re-poisoned each call, so
    // this must run every launch).
    transpose_ftw<<<(FEAT * FT_OUT) / 256, 256, 0, stream>>>(ft_w, ftT);

    // Kernel 2: 4 waves/block, one wave per board.
    nn_fwd<<<B_SZ / 4, 256, 0, stream>>>(stm_idx, nstm_idx, values, buckets,
                                         ftT, ft_b, out_w, out_b, out);
}

// Round 2
// 152.314 us; speedup vs baseline: 1.3856x; 1.3856x over previous
//
#include <hip/hip_runtime.h>
#include <hip/hip_bf16.h>
#include <math.h>

// Problem constants (fixed by the reference setup_inputs()).
#define B_SZ    16384
#define NNZ     32
#define FT_OUT  1024
#define FEAT    768
#define BUCKETS 8

typedef __attribute__((ext_vector_type(8))) short short8;

__device__ __forceinline__ float b2f(unsigned short u) {
    union { unsigned int i; float f; } x;
    x.i = ((unsigned int)u) << 16;
    return x.f;
}

// ---------------------------------------------------------------------------
// Kernel 1: tiled transpose + fp32->bf16 convert.
//   ft_w [FT_OUT][FEAT] fp32  ->  ftT [FEAT][FT_OUT] bf16
// 32x32 tiles via LDS (+1 pad), coalesced on both sides. ~4.5 MB traffic.
// ---------------------------------------------------------------------------
__global__ __launch_bounds__(256) void transpose_ftw_bf16(
    const float* __restrict__ ft_w, unsigned short* __restrict__ ftT) {
    __shared__ float tile[32][33];
    const int fo = blockIdx.x * 32;        // feature-block origin (0..767)
    const int oo = blockIdx.y * 32;        // output-block origin  (0..1023)
    const int tx = threadIdx.x & 31;
    const int ty = threadIdx.x >> 5;       // 0..7
#pragma unroll
    for (int i = 0; i < 4; ++i)            // read coalesced along FEAT
        tile[ty + 8 * i][tx] = ft_w[(oo + ty + 8 * i) * FEAT + fo + tx];
    __syncthreads();
#pragma unroll
    for (int i = 0; i < 4; ++i) {          // write coalesced along FT_OUT
        float v = tile[tx][ty + 8 * i];
        ftT[(fo + ty + 8 * i) * FT_OUT + oo + tx] =
            (unsigned short)(__bfloat16_as_ushort(__float2bfloat16(v)));
    }
}

// ---------------------------------------------------------------------------
// Kernel 2: one wave per board, bf16 gather table, fp32 accumulate.
// Lane L owns outputs {c*512 + 8L .. 8L+7} for c=0,1 -> per column-row each
// chunk is one fully-coalesced 1 KB wave load (64 lanes x 16 B of bf16).
// ---------------------------------------------------------------------------
__global__ __launch_bounds__(256) void nn_fwd(
    const int*            __restrict__ stm_idx,   // [B*NNZ*2] (board,feat)
    const int*            __restrict__ nstm_idx,  // [B*NNZ*2]
    const float*          __restrict__ values,    // [B*NNZ]
    const int*            __restrict__ buckets,   // [B]
    const unsigned short* __restrict__ ftT,       // [FEAT][FT_OUT] bf16
    const float*          __restrict__ ft_b,      // [FT_OUT] fp32
    const float*          __restrict__ out_w,     // [BUCKETS][2*FT_OUT] fp32
    const float*          __restrict__ out_b,     // [BUCKETS] fp32
    float*                __restrict__ out)       // [B]
{
    const int wave = threadIdx.x >> 6;
    const int lane = threadIdx.x & 63;
    const int b = __builtin_amdgcn_readfirstlane(blockIdx.x * 4 + wave);

    float acc_s[2][8], acc_n[2][8];
#pragma unroll
    for (int c = 0; c < 2; ++c) {
        const float4* fb = (const float4*)(ft_b + c * 512 + lane * 8);
        float4 b0 = fb[0], b1 = fb[1];
        acc_s[c][0] = b0.x; acc_s[c][1] = b0.y; acc_s[c][2] = b0.z; acc_s[c][3] = b0.w;
        acc_s[c][4] = b1.x; acc_s[c][5] = b1.y; acc_s[c][6] = b1.z; acc_s[c][7] = b1.w;
#pragma unroll
        for (int j = 0; j < 8; ++j) acc_n[c][j] = acc_s[c][j];
    }

    const int base = b * NNZ;

#pragma unroll 4
    for (int k = 0; k < NNZ; ++k) {
        const int   fs = stm_idx [(base + k) * 2 + 1];
        const int   fn = nstm_idx[(base + k) * 2 + 1];
        const float v  = values[base + k];
        const unsigned short* cs = ftT + fs * FT_OUT;
        const unsigned short* cn = ftT + fn * FT_OUT;
#pragma unroll
        for (int c = 0; c < 2; ++c) {
            short8 ws = *(const short8*)(cs + c * 512 + lane * 8);
            short8 wn = *(const short8*)(cn + c * 512 + lane * 8);
#pragma unroll
            for (int j = 0; j < 8; ++j) {
                acc_s[c][j] = fmaf(v, b2f((unsigned short)ws[j]), acc_s[c][j]);
                acc_n[c][j] = fmaf(v, b2f((unsigned short)wn[j]), acc_n[c][j]);
            }
        }
    }

    // ---- epilogue: clip, bucket-row dot, wave reduce, sigmoid ----
    const int bkt = __builtin_amdgcn_readfirstlane(buckets[b]);
    const float* ow = out_w + bkt * (2 * FT_OUT);

    float part = 0.0f;
#pragma unroll
    for (int c = 0; c < 2; ++c) {
        const float4* ps = (const float4*)(ow + c * 512 + lane * 8);
        const float4* pn = (const float4*)(ow + FT_OUT + c * 512 + lane * 8);
        float4 s0 = ps[0], s1 = ps[1], n0 = pn[0], n1 = pn[1];
        const float* wsp = &s0.x;   // s0,s1 contiguous? not guaranteed - unroll manually
        part += fminf(fmaxf(acc_s[c][0], 0.f), 1.f) * s0.x;
        part += fminf(fmaxf(acc_s[c][1], 0.f), 1.f) * s0.y;
        part += fminf(fmaxf(acc_s[c][2], 0.f), 1.f) * s0.z;
        part += fminf(fmaxf(acc_s[c][3], 0.f), 1.f) * s0.w;
        part += fminf(fmaxf(acc_s[c][4], 0.f), 1.f) * s1.x;
        part += fminf(fmaxf(acc_s[c][5], 0.f), 1.f) * s1.y;
        part += fminf(fmaxf(acc_s[c][6], 0.f), 1.f) * s1.z;
        part += fminf(fmaxf(acc_s[c][7], 0.f), 1.f) * s1.w;
        part += fminf(fmaxf(acc_n[c][0], 0.f), 1.f) * n0.x;
        part += fminf(fmaxf(acc_n[c][1], 0.f), 1.f) * n0.y;
        part += fminf(fmaxf(acc_n[c][2], 0.f), 1.f) * n0.z;
        part += fminf(fmaxf(acc_n[c][3], 0.f), 1.f) * n0.w;
        part += fminf(fmaxf(acc_n[c][4], 0.f), 1.f) * n1.x;
        part += fminf(fmaxf(acc_n[c][5], 0.f), 1.f) * n1.y;
        part += fminf(fmaxf(acc_n[c][6], 0.f), 1.f) * n1.z;
        part += fminf(fmaxf(acc_n[c][7], 0.f), 1.f) * n1.w;
        (void)wsp;
    }
#pragma unroll
    for (int off = 32; off >= 1; off >>= 1)
        part += __shfl_xor(part, off);

    if (lane == 0) {
        float logit = part + out_b[bkt];
        out[b] = 1.0f / (1.0f + expf(-logit));
    }
}

// ---------------------------------------------------------------------------
// setup_inputs() order:
//   0 stm_indices [B*32,2] int   1 nstm_indices [B*32,2] int
//   2 values [B*32] f32          3 buckets [B] int
//   4 size (scalar)              5 ft_w [1024,768] f32
//   6 ft_b [1024] f32            7 out_w [8,2048] f32
//   8 out_b [8] f32
// ---------------------------------------------------------------------------
extern "C" void kernel_launch(void* const* d_in, const int* in_sizes, int n_in,
                              void* d_out, int out_size, void* d_ws, size_t ws_size,
                              hipStream_t stream) {
    const int*   stm_idx  = (const int*)  d_in[0];
    const int*   nstm_idx = (const int*)  d_in[1];
    const float* values   = (const float*)d_in[2];
    const int*   buckets  = (const int*)  d_in[3];
    const float* ft_w     = (const float*)d_in[5];
    const float* ft_b     = (const float*)d_in[6];
    const float* out_w    = (const float*)d_in[7];
    const float* out_b    = (const float*)d_in[8];
    float*       out      = (float*)d_out;

    unsigned short* ftT = (unsigned short*)d_ws;   // [768][1024] bf16 = 1.5 MB

    // Kernel 1: transposed bf16 table (ws re-poisoned every call -> rebuild).
    transpose_ftw_bf16<<<dim3(FEAT / 32, FT_OUT / 32), 256, 0, stream>>>(ft_w, ftT);

    // Kernel 2: 4 waves/block, one wave per board.
    nn_fwd<<<B_SZ / 4, 256, 0, stream>>>(stm_idx, nstm_idx, values, buckets,
                                         ftT, ft_b, out_w, out_b, out);
}